// Round 2
// baseline (43.715 us; speedup 1.0000x reference)
//
#include <hip/hip_runtime.h>

#define BATCH 4
#define HH 128
#define WW 128
#define CC 64
#define PADR 2
#define NK 25          // 5x5 window slots
#define TH 8
#define TW 8
#define HALO 12        // TH + 4
#define HPOS 144       // 12*12
#define LSTRIDE 68     // 64 + 4 pad floats (272 B, 16B aligned, stride%32==4)

__global__ __launch_bounds__(256) void local_attn_kernel(
    const float* __restrict__ main_,
    const float* __restrict__ main_value,
    const float* __restrict__ ref,
    const float* __restrict__ ref_value,
    float* __restrict__ out)
{
    __shared__ float buf[HPOS * LSTRIDE];   // keys only (39168 B) -> 4 blocks/CU

    const int t    = threadIdx.x;
    const int blk  = blockIdx.x;            // b*256 + by*16 + bx
    const int bx   = blk & 15;
    const int by   = (blk >> 4) & 15;
    const int b    = blk >> 8;

    const int lane = t & 63;
    const int wave = t >> 6;
    const int pxl  = lane >> 2;             // 0..15 : pixel within wave
    const int cg   = lane & 3;              // channel quarter
    const int ly   = wave * 2 + (pxl >> 3); // 0..7
    const int lx   = pxl & 7;               // 0..7
    const int gy   = by * TH + ly;
    const int gx   = bx * TW + lx;

    const size_t img_base = (size_t)b * HH * WW * CC;
    const size_t px_off   = img_base + ((size_t)gy * WW + gx) * CC + cg * 16;

    const int y0 = by * TH - PADR;
    const int x0 = bx * TW - PADR;

    // ---- issue q + self-value loads FIRST (latency hides under staging) ----
    float q[16], mv[16];
    #pragma unroll
    for (int i = 0; i < 4; ++i) {
        float4 v = *(const float4*)(main_ + px_off + i * 4);
        q[i*4+0] = v.x; q[i*4+1] = v.y; q[i*4+2] = v.z; q[i*4+3] = v.w;
        float4 w = *(const float4*)(main_value + px_off + i * 4);
        mv[i*4+0] = w.x; mv[i*4+1] = w.y; mv[i*4+2] = w.z; mv[i*4+3] = w.w;
    }

    // ---- stage ref (key) halo: 12x12 x 64ch ----
    {
        const int c4 = t & 15;              // which float4 of the 64-ch row
        int pos = t >> 4;
        #pragma unroll
        for (int it = 0; it < 9; ++it, pos += 16) {
            int hy = pos / 12, hx = pos - hy * 12;
            int yy = y0 + hy, xx = x0 + hx;
            float4 v = make_float4(0.f, 0.f, 0.f, 0.f);
            if ((unsigned)yy < HH && (unsigned)xx < WW)
                v = *(const float4*)(ref + img_base + ((size_t)yy * WW + xx) * CC + c4 * 4);
            *(float4*)(buf + pos * LSTRIDE + c4 * 4) = v;
        }
    }

    __syncthreads();   // the ONLY barrier

    // ---- attention logits: 25 window dots + self dot ----
    float p[26];
    #pragma unroll
    for (int k = 0; k < NK; ++k) {
        const int di = k / 5, dj = k % 5;
        const float* base = buf + ((ly + di) * 12 + (lx + dj)) * LSTRIDE + cg * 16;
        float acc = 0.f;
        #pragma unroll
        for (int i = 0; i < 4; ++i) {
            float4 v = *(const float4*)(base + i * 4);
            acc += q[i*4+0]*v.x + q[i*4+1]*v.y + q[i*4+2]*v.z + q[i*4+3]*v.w;
        }
        // reduce over the 4 channel-quarter lanes (DPP quad-perm)
        acc += __shfl_xor(acc, 1);
        acc += __shfl_xor(acc, 2);
        p[k] = acc;
    }
    {
        float acc = 0.f;
        #pragma unroll
        for (int c = 0; c < 16; ++c) acc += q[c] * q[c];
        acc += __shfl_xor(acc, 1);
        acc += __shfl_xor(acc, 2);
        p[25] = acc;
    }

    // ---- softmax (deferred normalization) ----
    float m = p[0];
    #pragma unroll
    for (int k = 1; k < 26; ++k) m = fmaxf(m, p[k]);
    float s = 0.f;
    #pragma unroll
    for (int k = 0; k < 26; ++k) { p[k] = __expf(p[k] - m); s += p[k]; }
    const float rs = 1.f / s;

    // ---- aggregation: values straight from global (L1/L2 reuse), no barrier ----
    float acc[16];
    #pragma unroll
    for (int c = 0; c < 16; ++c) acc[c] = 0.f;

    #pragma unroll
    for (int k = 0; k < NK; ++k) {
        const int di = k / 5, dj = k % 5;
        const int yy = gy + di - PADR, xx = gx + dj - PADR;
        const float pk = p[k];
        if ((unsigned)yy < HH && (unsigned)xx < WW) {
            const float* base = ref_value + img_base + ((size_t)yy * WW + xx) * CC + cg * 16;
            #pragma unroll
            for (int i = 0; i < 4; ++i) {
                float4 v = *(const float4*)(base + i * 4);
                acc[i*4+0] += pk * v.x; acc[i*4+1] += pk * v.y;
                acc[i*4+2] += pk * v.z; acc[i*4+3] += pk * v.w;
            }
        }
    }
    {   // self slot: preloaded main_value
        const float pk = p[25];
        #pragma unroll
        for (int c = 0; c < 16; ++c) acc[c] += pk * mv[c];
    }

    #pragma unroll
    for (int i = 0; i < 4; ++i) {
        float4 v = make_float4(acc[i*4+0]*rs, acc[i*4+1]*rs,
                               acc[i*4+2]*rs, acc[i*4+3]*rs);
        *(float4*)(out + px_off + i * 4) = v;
    }
}

extern "C" void kernel_launch(void* const* d_in, const int* in_sizes, int n_in,
                              void* d_out, int out_size, void* d_ws, size_t ws_size,
                              hipStream_t stream) {
    const float* main_      = (const float*)d_in[0];
    const float* main_value = (const float*)d_in[1];
    const float* ref        = (const float*)d_in[2];
    const float* ref_value  = (const float*)d_in[3];
    float* out = (float*)d_out;

    local_attn_kernel<<<dim3(BATCH * 16 * 16), dim3(256), 0, stream>>>(
        main_, main_value, ref, ref_value, out);
}

// Round 3
// 26.976 us; speedup vs baseline: 1.6205x; 1.6205x over previous
//
#include <hip/hip_runtime.h>

#define BATCH 4
#define HH 128
#define WW 128
#define CC 64
#define PADR 2
#define NK 25          // 5x5 window slots
#define TH 8
#define TW 8
#define HALO 12        // TH + 4
#define HPOS 144       // 12*12
#define LSTRIDE 68     // 64 + 4 pad floats (272 B, 16B aligned, stride%32==4)

__global__ __launch_bounds__(256, 4) void local_attn_kernel(
    const float* __restrict__ main_,
    const float* __restrict__ main_value,
    const float* __restrict__ ref,
    const float* __restrict__ ref_value,
    float* __restrict__ out)
{
    __shared__ float buf[HPOS * LSTRIDE];   // 39168 B; keys, then reused for values

    const int t    = threadIdx.x;
    // XCD-aware swizzle: nwg=1024 divisible by 8 -> simple form is bijective
    const int nwg  = BATCH * 16 * 16;
    const int cpx  = nwg >> 3;
    const int blk  = (blockIdx.x & 7) * cpx + (blockIdx.x >> 3);
    const int bx   = blk & 15;
    const int by   = (blk >> 4) & 15;
    const int b    = blk >> 8;

    const int lane = t & 63;
    const int wave = t >> 6;
    const int pxl  = lane >> 2;             // 0..15 : pixel within wave
    const int cg   = lane & 3;              // channel quarter
    const int ly   = wave * 2 + (pxl >> 3); // 0..7
    const int lx   = pxl & 7;               // 0..7
    const int gy   = by * TH + ly;
    const int gx   = bx * TW + lx;

    const size_t img_base = (size_t)b * HH * WW * CC;
    const size_t px_off   = img_base + ((size_t)gy * WW + gx) * CC + cg * 16;

    const int y0 = by * TH - PADR;
    const int x0 = bx * TW - PADR;

    const int c4   = t & 15;                // which float4 of a 64-ch row
    const int pos0 = t >> 4;                // first halo position for this thread

    // ---- issue ALL global loads up front ----
    // q (my 16 channels)
    float4 qv[4];
    #pragma unroll
    for (int i = 0; i < 4; ++i)
        qv[i] = *(const float4*)(main_ + px_off + i * 4);

    // key halo -> regs
    float4 kreg[9];
    #pragma unroll
    for (int it = 0; it < 9; ++it) {
        int pos = pos0 + 16 * it;
        int hy = pos / 12, hx = pos - hy * 12;
        int yy = y0 + hy, xx = x0 + hx;
        kreg[it] = make_float4(0.f, 0.f, 0.f, 0.f);
        if ((unsigned)yy < HH && (unsigned)xx < WW)
            kreg[it] = *(const float4*)(ref + img_base + ((size_t)yy * WW + xx) * CC + c4 * 4);
    }

    // value halo -> regs (stay in flight / in regs through the logits phase)
    float4 vstage[9];
    #pragma unroll
    for (int it = 0; it < 9; ++it) {
        int pos = pos0 + 16 * it;
        int hy = pos / 12, hx = pos - hy * 12;
        int yy = y0 + hy, xx = x0 + hx;
        vstage[it] = make_float4(0.f, 0.f, 0.f, 0.f);
        if ((unsigned)yy < HH && (unsigned)xx < WW)
            vstage[it] = *(const float4*)(ref_value + img_base + ((size_t)yy * WW + xx) * CC + c4 * 4);
    }

    // ---- keys -> LDS ----
    #pragma unroll
    for (int it = 0; it < 9; ++it)
        *(float4*)(buf + (pos0 + 16 * it) * LSTRIDE + c4 * 4) = kreg[it];

    __syncthreads();   // B1: keys visible

    // ---- attention logits: 25 window dots + self dot ----
    float q[16];
    #pragma unroll
    for (int i = 0; i < 4; ++i) {
        q[i*4+0] = qv[i].x; q[i*4+1] = qv[i].y; q[i*4+2] = qv[i].z; q[i*4+3] = qv[i].w;
    }

    float p[26];
    const float* mybase = buf + (ly * 12 + lx) * LSTRIDE + cg * 16;
    #pragma unroll
    for (int k = 0; k < NK; ++k) {
        const int di = k / 5, dj = k % 5;
        const float* base = mybase + (di * 12 + dj) * LSTRIDE;  // compile-time imm offset
        float acc = 0.f;
        #pragma unroll
        for (int i = 0; i < 4; ++i) {
            float4 v = *(const float4*)(base + i * 4);
            acc += q[i*4+0]*v.x + q[i*4+1]*v.y + q[i*4+2]*v.z + q[i*4+3]*v.w;
        }
        acc += __shfl_xor(acc, 1);
        acc += __shfl_xor(acc, 2);
        p[k] = acc;
    }
    {
        float acc = 0.f;
        #pragma unroll
        for (int c = 0; c < 16; ++c) acc += q[c] * q[c];
        acc += __shfl_xor(acc, 1);
        acc += __shfl_xor(acc, 2);
        p[25] = acc;
    }

    // ---- softmax (deferred normalization) ----
    float m = p[0];
    #pragma unroll
    for (int k = 1; k < 26; ++k) m = fmaxf(m, p[k]);
    float s = 0.f;
    #pragma unroll
    for (int k = 0; k < 26; ++k) { p[k] = __expf(p[k] - m); s += p[k]; }
    const float rs = 1.f / s;

    __syncthreads();   // B2: everyone done reading keys

    // ---- values -> LDS (from regs; loads long since landed) ----
    #pragma unroll
    for (int it = 0; it < 9; ++it)
        *(float4*)(buf + (pos0 + 16 * it) * LSTRIDE + c4 * 4) = vstage[it];

    __syncthreads();   // B3: values visible

    // ---- self value load (latency hides under aggregation startup) ----
    float4 mvv[4];
    #pragma unroll
    for (int i = 0; i < 4; ++i)
        mvv[i] = *(const float4*)(main_value + px_off + i * 4);

    // ---- aggregation: out[c] = sum_k p_k * value_k[c] ----
    float acc[16];
    #pragma unroll
    for (int c = 0; c < 16; ++c) acc[c] = 0.f;

    #pragma unroll
    for (int k = 0; k < NK; ++k) {
        const int di = k / 5, dj = k % 5;
        const float* base = mybase + (di * 12 + dj) * LSTRIDE;
        const float pk = p[k];
        #pragma unroll
        for (int i = 0; i < 4; ++i) {
            float4 v = *(const float4*)(base + i * 4);
            acc[i*4+0] += pk * v.x; acc[i*4+1] += pk * v.y;
            acc[i*4+2] += pk * v.z; acc[i*4+3] += pk * v.w;
        }
    }
    {   // self slot
        const float pk = p[25];
        #pragma unroll
        for (int i = 0; i < 4; ++i) {
            acc[i*4+0] += pk * mvv[i].x; acc[i*4+1] += pk * mvv[i].y;
            acc[i*4+2] += pk * mvv[i].z; acc[i*4+3] += pk * mvv[i].w;
        }
    }

    #pragma unroll
    for (int i = 0; i < 4; ++i) {
        float4 v = make_float4(acc[i*4+0]*rs, acc[i*4+1]*rs,
                               acc[i*4+2]*rs, acc[i*4+3]*rs);
        *(float4*)(out + px_off + i * 4) = v;
    }
}

extern "C" void kernel_launch(void* const* d_in, const int* in_sizes, int n_in,
                              void* d_out, int out_size, void* d_ws, size_t ws_size,
                              hipStream_t stream) {
    const float* main_      = (const float*)d_in[0];
    const float* main_value = (const float*)d_in[1];
    const float* ref        = (const float*)d_in[2];
    const float* ref_value  = (const float*)d_in[3];
    float* out = (float*)d_out;

    local_attn_kernel<<<dim3(BATCH * 16 * 16), dim3(256), 0, stream>>>(
        main_, main_value, ref, ref_value, out);
}